// Round 12
// baseline (289.654 us; speedup 1.0000x reference)
//
#include <hip/hip_runtime.h>

#define NS 8192
#define EMBED 128
#define ROWCHUNK 512             // 16 chunks of 512 rows
#define NPANEL (ROWCHUNK / 32)   // 16 panels of 32 rows
#define NPOSBLK 100              // one pos-block per class
#define BSTRIDE 256              // bucket stride per class (max class size)
#define AROW 12                  // correction-hist row stride (11 bins + 1 pad)
#define INV64K (1.0f / 65536.0f)

typedef __bf16 bf16x8 __attribute__((ext_vector_type(8)));
typedef float f32x4 __attribute__((ext_vector_type(4)));
typedef float f32x2 __attribute__((ext_vector_type(2)));
typedef const __attribute__((address_space(1))) unsigned ag_u32;  // global
typedef __attribute__((address_space(3))) unsigned al_u32;        // LDS

// workspace layout (bytes from ws start)
#define OFF_XB  0u               // bf16 [8192][128] = 2 MiB (row-granule-XOR-swizzled)
#define OFF_GS  2097152u         // q16  [8192][4]   cumulative C bins 3..6 (all pairs)
#define OFF_GSP 2228224u         // q16  [8192][4]   cumulative Cp bins 3..6 (positives)
#define OFF_GA  2359296u         // q16  [8192][12]  all-hist corrections
#define OFF_GAP 2752512u         // q16  [8192][12]  pos-hist corrections
#define OFF_CC  3145728u         // int  [100] class counts (cursor)
#define OFF_AC  3146240u         // float[2] accum + u32 done
#define OFF_BK  3146752u         // int  [100][256] class member buckets (100 KB)
#define ZERO_U4 65536u           // OFF_GS..OFF_CC zeroed by prep (uint4 count)

__device__ inline unsigned short f2bf(float f) {
  unsigned u = __float_as_uint(f);
  u += 0x7fffu + ((u >> 16) & 1u);   // round-to-nearest-even
  return (unsigned short)(u >> 16);
}
__device__ inline float clamp01(float x) { return __builtin_amdgcn_fmed3f(x, 0.f, 1.f); }
__device__ inline f32x2 pkclamp01(f32x2 v) {
  return __builtin_elementwise_min(__builtin_elementwise_max(v, (f32x2){0.f, 0.f}),
                                   (f32x2){1.f, 1.f});
}

// ---- prep: fp32->bf16 swizzled convert + zero accumulators + class scatter ----
__global__ __launch_bounds__(256) void prep_kernel(const float* __restrict__ x,
                                                   const int* __restrict__ labels,
                                                   unsigned short* __restrict__ xb,
                                                   uint4* __restrict__ zbase,
                                                   int* __restrict__ cnt,
                                                   int* __restrict__ bucket) {
  const int gid = blockIdx.x * 256 + threadIdx.x;   // 131072 threads: row*16+granule
  const int row = gid >> 4, g = gid & 15;
  const float4 v0 = reinterpret_cast<const float4*>(x)[row * 32 + g * 2];
  const float4 v1 = reinterpret_cast<const float4*>(x)[row * 32 + g * 2 + 1];
  uint4 o;
  o.x = (unsigned)f2bf(v0.x) | ((unsigned)f2bf(v0.y) << 16);
  o.y = (unsigned)f2bf(v0.z) | ((unsigned)f2bf(v0.w) << 16);
  o.z = (unsigned)f2bf(v1.x) | ((unsigned)f2bf(v1.y) << 16);
  o.w = (unsigned)f2bf(v1.z) | ((unsigned)f2bf(v1.w) << 16);
  reinterpret_cast<uint4*>(xb)[row * 16 + (g ^ (row & 7))] = o;
  if (gid < (int)ZERO_U4) zbase[gid] = make_uint4(0u, 0u, 0u, 0u);
  if (gid < NS) {                     // class bucket scatter (cnt pre-zeroed by memset)
    const int lab = labels[gid];
    const int slot = atomicAdd(&cnt[lab], 1);
    if (slot < BSTRIDE) bucket[lab * BSTRIDE + slot] = gid;
  }
}

// ---- main: blocks 0..99 = per-class positive pass; blocks 100.. = all-pairs ----
__global__ __launch_bounds__(256, 8) void fastap_main_kernel(
    const unsigned short* __restrict__ xb,
    unsigned* __restrict__ gS, unsigned* __restrict__ gSp,
    unsigned* __restrict__ gA, unsigned* __restrict__ gAp,
    const int* __restrict__ cnt, const int* __restrict__ bucket) {
  __shared__ __align__(16) unsigned short sA[2][32 * 128];  // 2 x 8KB row panels

  const int tid = threadIdx.x;

  if (blockIdx.x < NPOSBLK) {
    // ---------- positive pass: class c, thread t owns member row t ----------
    const int c = blockIdx.x;
    const int n = min(cnt[c], BSTRIDE);
    const int i = tid;
    if (i >= n) return;
    const int gi = bucket[c * BSTRIDE + i];
    const uint4* pa = reinterpret_cast<const uint4*>(xb + gi * 128);
    const int sw_a = gi & 7;
    float B[4] = {0.f, 0.f, 0.f, 0.f};
    for (int j = 0; j < n; ++j) {
      if (j == i) continue;
      const int gj = bucket[c * BSTRIDE + j];
      const uint4* pb = reinterpret_cast<const uint4*>(xb + gj * 128);
      const int sw_b = gj & 7;
      float acc = 0.f;
      #pragma unroll
      for (int g = 0; g < 16; ++g) {            // logical granule g (order-free dot)
        const uint4 av = pa[g ^ sw_a];
        const uint4 bv = pb[g ^ sw_b];
        const unsigned au[4] = {av.x, av.y, av.z, av.w};
        const unsigned bu[4] = {bv.x, bv.y, bv.z, bv.w};
        #pragma unroll
        for (int w = 0; w < 4; ++w) {           // 2 bf16 per u32: lo<<16, hi&mask
          acc = fmaf(__uint_as_float(au[w] << 16),
                     __uint_as_float(bu[w] << 16), acc);
          acc = fmaf(__uint_as_float(au[w] & 0xffff0000u),
                     __uint_as_float(bu[w] & 0xffff0000u), acc);
        }
      }
      const float a = acc;                      // cos(gi, gj)
      B[0] += clamp01(fmaf(a, 5.f, -1.f));
      B[1] += clamp01(a * 5.f);
      B[2] += clamp01(fmaf(a, 5.f, 1.f));
      B[3] += clamp01(fmaf(a, 5.f, 2.f));
      if (__builtin_expect(fabsf(a) > 0.4f, 0)) {   // rare outlier corrections
        const float t = fmaf(a, -5.f, 5.f);
        #pragma unroll
        for (int k = 0; k <= 2; ++k) {
          const int q = (int)(clamp01((float)(k + 1) - t) * 65536.f + 0.5f);
          if (q) atomicAdd(&gAp[gi * AROW + k], (unsigned)q);
        }
        #pragma unroll
        for (int k = 7; k <= 10; ++k) {
          const int q = (int)((clamp01((float)(k + 1) - t) - 1.f) * 65536.f - 0.5f);
          if (q) atomicAdd(&gAp[gi * AROW + k], (unsigned)q);
        }
      }
    }
    #pragma unroll
    for (int k = 0; k < 4; ++k)
      atomicAdd(&gSp[gi * 4 + k], (unsigned)(int)lrintf(B[k] * 65536.f));
    return;
  }

  // ---------- all-pairs pass (label-free): 16-col B frags, streamed A panels ----
  const int mb   = blockIdx.x - NPOSBLK;
  const int wave = tid >> 6;
  const int lane = tid & 63;
  const int l16  = lane & 15;
  const int quad = lane >> 4;
  const int colBase  = (mb & 127) * 64;
  const int rowChunk = (mb >> 7) * ROWCHUNK;

  const int jcol = colBase + wave * 16 + l16;
  bf16x8 bfr[4];
  #pragma unroll
  for (int kb = 0; kb < 4; ++kb) {
    const int pg = (kb * 4 + quad) ^ (l16 & 7);
    bfr[kb] = *reinterpret_cast<const bf16x8*>(&xb[jcol * 128 + pg * 8]);
  }

  f32x2 C01 = {0.f, 0.f}, C23 = {0.f, 0.f};

  int aOff[4];
  #pragma unroll
  for (int kb = 0; kb < 4; ++kb)
    aOff[kb] = l16 * 128 + (((kb * 4 + quad) ^ (l16 & 7)) << 3);

  const unsigned short* xrb = xb + rowChunk * 128;
  auto stage = [&](int p, int b) {
    const unsigned short* src = xrb + p * (32 * 128);
    __builtin_amdgcn_global_load_lds((ag_u32*)(src + tid * 8),
                                     (al_u32*)(&sA[b][tid * 8]), 16, 0, 0);
    __builtin_amdgcn_global_load_lds((ag_u32*)(src + (tid + 256) * 8),
                                     (al_u32*)(&sA[b][(tid + 256) * 8]), 16, 0, 0);
  };

  auto tile16 = [&](const unsigned short* ap, int lcr) {
    bf16x8 a0 = *reinterpret_cast<const bf16x8*>(&ap[aOff[0]]);
    bf16x8 a1 = *reinterpret_cast<const bf16x8*>(&ap[aOff[1]]);
    bf16x8 a2 = *reinterpret_cast<const bf16x8*>(&ap[aOff[2]]);
    bf16x8 a3 = *reinterpret_cast<const bf16x8*>(&ap[aOff[3]]);
    f32x4 acc = {0.f, 0.f, 0.f, 0.f};
    acc = __builtin_amdgcn_mfma_f32_16x16x32_bf16(a0, bfr[0], acc, 0, 0, 0);
    acc = __builtin_amdgcn_mfma_f32_16x16x32_bf16(a1, bfr[1], acc, 0, 0, 0);
    acc = __builtin_amdgcn_mfma_f32_16x16x32_bf16(a2, bfr[2], acc, 0, 0, 0);
    acc = __builtin_amdgcn_mfma_f32_16x16x32_bf16(a3, bfr[3], acc, 0, 0, 0);

    // fast path: bins 3..6 exact for all t: H[k] = clamp01(5a + (k-4))
    #pragma unroll
    for (int r = 0; r < 4; ++r) {
      const f32x2 av = {acc[r], acc[r]};
      C01 += pkclamp01(__builtin_elementwise_fma(av, (f32x2){5.f, 5.f},
                                                 (f32x2){-1.f, 0.f}));
      C23 += pkclamp01(__builtin_elementwise_fma(av, (f32x2){5.f, 5.f},
                                                 (f32x2){1.f, 2.f}));
    }

    const float mabs = fmaxf(fmaxf(fabsf(acc[0]), fabsf(acc[1])),
                             fmaxf(fabsf(acc[2]), fabsf(acc[3])));
    if (__builtin_expect(mabs > 0.4f, 0)) {
      #pragma unroll
      for (int r = 0; r < 4; ++r) {
        const float a = acc[r];
        if (fabsf(a) <= 0.4f) continue;
        const int i = rowChunk + lcr + quad * 4 + r;
        const float d0 = clamp01(fmaf(a, 5.f, -1.f));
        const float d1 = clamp01(a * 5.f);
        const float d2 = clamp01(fmaf(a, 5.f, 1.f));
        const float d3 = clamp01(fmaf(a, 5.f, 2.f));
        if (i == jcol) {
          // diagonal: cancel fast contributions + bins>=7 base (+1)
          C01 -= (f32x2){d0, d1};  C23 -= (f32x2){d2, d3};
          #pragma unroll
          for (int k = 7; k <= 10; ++k)
            atomicAdd(&gA[jcol * AROW + k], (unsigned)(-65536));
        } else {
          const float t = fmaf(a, -5.f, 5.f);
          #pragma unroll
          for (int k = 0; k <= 2; ++k) {       // assumed cumulative 0
            const int q = (int)(clamp01((float)(k + 1) - t) * 65536.f + 0.5f);
            if (q) atomicAdd(&gA[jcol * AROW + k], (unsigned)q);
          }
          #pragma unroll
          for (int k = 7; k <= 10; ++k) {      // assumed cumulative 1
            const int q = (int)((clamp01((float)(k + 1) - t) - 1.f) * 65536.f - 0.5f);
            if (q) atomicAdd(&gA[jcol * AROW + k], (unsigned)q);
          }
        }
      }
    }
  };

  stage(0, 0);
  __syncthreads();             // panel 0 drained

  #pragma unroll 1
  for (int p = 0; p < NPANEL; ++p) {
    const int cur = p & 1;
    if (p + 1 < NPANEL) stage(p + 1, cur ^ 1);   // async DMA behind this panel
    tile16(&sA[cur][0],        p * 32);
    tile16(&sA[cur][16 * 128], p * 32 + 16);
    __syncthreads();
  }

  // reduce across the 4 quads sharing each column (lane ^16, ^32)
  #pragma unroll
  for (int m = 16; m < 64; m <<= 1) {
    C01.x += __shfl_xor(C01.x, m, 64); C01.y += __shfl_xor(C01.y, m, 64);
    C23.x += __shfl_xor(C23.x, m, 64); C23.y += __shfl_xor(C23.y, m, 64);
  }

  if (quad == 0) {
    const float Cv[4] = {C01.x, C01.y, C23.x, C23.y};
    #pragma unroll
    for (int k = 0; k < 4; ++k)
      atomicAdd(&gS[jcol * 4 + k], (unsigned)(int)lrintf(Cv[k] * 65536.f));
  }
}

// ---- epilogue: per-row AP + final loss (last block finalizes) ----
__global__ __launch_bounds__(256) void epilogue_kernel(
    const unsigned* __restrict__ gS, const unsigned* __restrict__ gSp,
    const unsigned* __restrict__ gA, const unsigned* __restrict__ gAp,
    const int* __restrict__ labels, const int* __restrict__ cnt,
    float* __restrict__ accum, unsigned* __restrict__ done,
    float* __restrict__ out) {
  const int i = blockIdx.x * 256 + threadIdx.x;
  const int np = cnt[labels[i]] - 1;   // N_pos = classCount - 1
  float ap = 0.f, val = 0.f, HpPrev = 0.f;
  #pragma unroll
  for (int b = 0; b <= 10; ++b) {
    const float baseH  = (b < 3) ? 0.f
                       : (b < 7) ? (float)(int)gS[i * 4 + (b - 3)]  * INV64K : 8192.f;
    const float basePp = (b < 3) ? 0.f
                       : (b < 7) ? (float)(int)gSp[i * 4 + (b - 3)] * INV64K : (float)np;
    const float H  = baseH  + (float)(int)gA[i * AROW + b]  * INV64K;
    const float Hp = basePp + (float)(int)gAp[i * AROW + b] * INV64K;
    const float hp = Hp - HpPrev;
    HpPrev = Hp;
    if (H > 1e-6f) ap += hp * Hp / H;
  }
  if (np > 0) { ap /= (float)np; val = 1.f; } else ap = 0.f;

  __shared__ float sa[256], sv[256];
  sa[threadIdx.x] = ap; sv[threadIdx.x] = val;
  __syncthreads();
  for (int s = 128; s > 0; s >>= 1) {
    if (threadIdx.x < s) {
      sa[threadIdx.x] += sa[threadIdx.x + s];
      sv[threadIdx.x] += sv[threadIdx.x + s];
    }
    __syncthreads();
  }
  if (threadIdx.x == 0) {
    atomicAdd(&accum[0], sa[0]);
    atomicAdd(&accum[1], sv[0]);
    __threadfence();
    const unsigned prev = atomicAdd(done, 1u);
    if (prev == gridDim.x - 1) {
      const float a = atomicAdd(&accum[0], 0.f);   // coherent reads
      const float c = atomicAdd(&accum[1], 0.f);
      out[0] = 1.f - (c > 0.f ? a / c : 0.f);
    }
  }
}

extern "C" void kernel_launch(void* const* d_in, const int* in_sizes, int n_in,
                              void* d_out, int out_size, void* d_ws, size_t ws_size,
                              hipStream_t stream) {
  const float* x      = (const float*)d_in[0];
  const int*   labels = (const int*)d_in[1];
  float* out = (float*)d_out;

  char* ws = (char*)d_ws;
  unsigned short* xb = (unsigned short*)(ws + OFF_XB);
  unsigned* gS   = (unsigned*)(ws + OFF_GS);
  unsigned* gSp  = (unsigned*)(ws + OFF_GSP);
  unsigned* gA   = (unsigned*)(ws + OFF_GA);
  unsigned* gAp  = (unsigned*)(ws + OFF_GAP);
  int*      cnt  = (int*)(ws + OFF_CC);
  float*    accum = (float*)(ws + OFF_AC);
  unsigned* done  = (unsigned*)(ws + OFF_AC + 8);
  int*      bucket = (int*)(ws + OFF_BK);

  // zero class counters + accum/done BEFORE prep's atomic scatter
  hipMemsetAsync(ws + OFF_CC, 0, 1024, stream);
  prep_kernel<<<512, 256, 0, stream>>>(x, labels, xb, (uint4*)(ws + OFF_GS),
                                       cnt, bucket);
  fastap_main_kernel<<<NPOSBLK + (NS / 64) * (NS / ROWCHUNK), 256, 0, stream>>>(
      xb, gS, gSp, gA, gAp, cnt, bucket);
  epilogue_kernel<<<NS / 256, 256, 0, stream>>>(gS, gSp, gA, gAp, labels, cnt,
                                                accum, done, out);
}

// Round 13
// 118.166 us; speedup vs baseline: 2.4512x; 2.4512x over previous
//
#include <hip/hip_runtime.h>

#define NS 8192
#define EMBED 128
#define ROWCHUNK 512             // grid.y = 16 chunks of 512 rows
#define NPANEL (ROWCHUNK / 32)   // 16 panels of 32 rows
#define AROW 12                  // correction-hist row stride (11 bins + 1 pad)
#define INV64K (1.0f / 65536.0f)

typedef __bf16 bf16x8 __attribute__((ext_vector_type(8)));
typedef float f32x4 __attribute__((ext_vector_type(4)));
typedef float f32x2 __attribute__((ext_vector_type(2)));
typedef const __attribute__((address_space(1))) unsigned ag_u32;  // global
typedef __attribute__((address_space(3))) unsigned al_u32;        // LDS

// workspace layout (bytes from ws start). Rows are CLASS-SORTED in xb.
#define OFF_XB    0u             // bf16 [8192][128] = 2 MiB (sorted + row-swizzled)
#define OFF_GS    2097152u       // q16  [8192][4]   cumulative C bins 3..6 (all pairs)
#define OFF_GSP   2228224u       // q16  [8192][4]   cumulative Cp bins 3..6 (positives)
#define OFF_GA    2359296u       // q16  [8192][12]  all-hist corrections
#define OFF_GAP   2752512u       // q16  [8192][12]  pos-hist corrections
#define OFF_AC    3145728u       // float[2] accum + u32 done (64B reserved)
#define OFF_CNT   3145792u       // int  [128] class counts
#define OFF_OFS   3146304u       // int  [128] class start offsets (exclusive prefix)
#define OFF_INTRA 3146816u       // int  [8192] intra-class index per original row
#define OFF_CLS   3179584u       // int  [8192] class id per SORTED row
#define ZERO_U4   65537u         // uint4s covering OFF_GS .. OFF_AC+16

__device__ inline float clamp01(float x) { return __builtin_amdgcn_fmed3f(x, 0.f, 1.f); }
__device__ inline f32x2 pkclamp01(f32x2 v) {
  return __builtin_elementwise_min(__builtin_elementwise_max(v, (f32x2){0.f, 0.f}),
                                   (f32x2){1.f, 1.f});
}
__device__ inline unsigned short f2bf(float f) {
  unsigned u = __float_as_uint(f);
  u += 0x7fffu + ((u >> 16) & 1u);   // round-to-nearest-even
  return (unsigned short)(u >> 16);
}

// ---- prep A (1 block): class counts + intra-class index + prefix offsets ----
__global__ __launch_bounds__(256) void prep_count_kernel(const int* __restrict__ labels,
                                                         int* __restrict__ cnt,
                                                         int* __restrict__ ofs,
                                                         int* __restrict__ intra) {
  __shared__ int c[128];
  const int tid = threadIdx.x;
  if (tid < 128) c[tid] = 0;
  __syncthreads();
  for (int i = tid; i < NS; i += 256)
    intra[i] = atomicAdd(&c[labels[i]], 1);
  __syncthreads();
  if (tid == 0) {
    int run = 0;
    for (int k = 0; k < 128; ++k) { ofs[k] = run; cnt[k] = c[k]; run += c[k]; }
  }
}

// ---- prep B: fp32->bf16 convert, scattered to sorted+swizzled layout; zero accs ----
__global__ __launch_bounds__(256) void prep_scatter_kernel(
    const float* __restrict__ x, const int* __restrict__ labels,
    const int* __restrict__ ofs, const int* __restrict__ intra,
    unsigned short* __restrict__ xb, int* __restrict__ classOf,
    uint4* __restrict__ zbase) {
  const int gid = blockIdx.x * 256 + threadIdx.x;   // 131072 threads: row*16+granule
  const int row = gid >> 4, g = gid & 15;
  const int lab = labels[row];
  const int slot = ofs[lab] + intra[row];           // sorted position
  const float4 v0 = reinterpret_cast<const float4*>(x)[row * 32 + g * 2];
  const float4 v1 = reinterpret_cast<const float4*>(x)[row * 32 + g * 2 + 1];
  uint4 o;
  o.x = (unsigned)f2bf(v0.x) | ((unsigned)f2bf(v0.y) << 16);
  o.y = (unsigned)f2bf(v0.z) | ((unsigned)f2bf(v0.w) << 16);
  o.z = (unsigned)f2bf(v1.x) | ((unsigned)f2bf(v1.y) << 16);
  o.w = (unsigned)f2bf(v1.z) | ((unsigned)f2bf(v1.w) << 16);
  reinterpret_cast<uint4*>(xb)[slot * 16 + (g ^ (slot & 7))] = o;
  if (g == 0) classOf[slot] = lab;
  if (gid < (int)ZERO_U4) zbase[gid] = make_uint4(0u, 0u, 0u, 0u);
}

// ---- main: R10 structure, label-free. Positives = contiguous sorted range. ----
__global__ __launch_bounds__(256, 8) void fastap_main_kernel(
    const unsigned short* __restrict__ xb,
    const int* __restrict__ classOf, const int* __restrict__ cnt,
    const int* __restrict__ ofs,
    unsigned* __restrict__ gS, unsigned* __restrict__ gSp,
    unsigned* __restrict__ gA, unsigned* __restrict__ gAp) {
  __shared__ __align__(16) unsigned short sA[2][32 * 128];  // 2 x 8KB row panels

  const int tid  = threadIdx.x;
  const int wave = tid >> 6;
  const int lane = tid & 63;
  const int l16  = lane & 15;
  const int quad = lane >> 4;
  const int colBase  = blockIdx.x * 64;       // 128 col strips (sorted cols)
  const int rowChunk = blockIdx.y * ROWCHUNK; // 16 row chunks (sorted rows)

  // fixed B fragments: this wave's 16 sorted cols, K=128 (jcol&7 == l16&7)
  const int jcol = colBase + wave * 16 + l16;
  bf16x8 bfr[4];
  #pragma unroll
  for (int kb = 0; kb < 4; ++kb) {
    const int pg = (kb * 4 + quad) ^ (l16 & 7);
    bfr[kb] = *reinterpret_cast<const bf16x8*>(&xb[jcol * 128 + pg * 8]);
  }
  const int ci = classOf[jcol];
  const int lo = ofs[ci];             // positive rows for this column: [lo, hi)
  const int hi = lo + cnt[ci];

  f32x2 C01 = {0.f, 0.f}, C23 = {0.f, 0.f};     // all-pairs bins 3..6 (cumulative)
  f32x2 Cp01 = {0.f, 0.f}, Cp23 = {0.f, 0.f};   // positive bins 3..6

  int aOff[4];
  #pragma unroll
  for (int kb = 0; kb < 4; ++kb)
    aOff[kb] = l16 * 128 + (((kb * 4 + quad) ^ (l16 & 7)) << 3);

  const unsigned short* xrb = xb + rowChunk * 128;
  auto stage = [&](int p, int b) {
    const unsigned short* src = xrb + p * (32 * 128);
    __builtin_amdgcn_global_load_lds((ag_u32*)(src + tid * 8),
                                     (al_u32*)(&sA[b][tid * 8]), 16, 0, 0);
    __builtin_amdgcn_global_load_lds((ag_u32*)(src + (tid + 256) * 8),
                                     (al_u32*)(&sA[b][(tid + 256) * 8]), 16, 0, 0);
  };

  auto tile16 = [&](const unsigned short* ap, int lcr) {
    bf16x8 a0 = *reinterpret_cast<const bf16x8*>(&ap[aOff[0]]);
    bf16x8 a1 = *reinterpret_cast<const bf16x8*>(&ap[aOff[1]]);
    bf16x8 a2 = *reinterpret_cast<const bf16x8*>(&ap[aOff[2]]);
    bf16x8 a3 = *reinterpret_cast<const bf16x8*>(&ap[aOff[3]]);
    f32x4 acc = {0.f, 0.f, 0.f, 0.f};
    acc = __builtin_amdgcn_mfma_f32_16x16x32_bf16(a0, bfr[0], acc, 0, 0, 0);
    acc = __builtin_amdgcn_mfma_f32_16x16x32_bf16(a1, bfr[1], acc, 0, 0, 0);
    acc = __builtin_amdgcn_mfma_f32_16x16x32_bf16(a2, bfr[2], acc, 0, 0, 0);
    acc = __builtin_amdgcn_mfma_f32_16x16x32_bf16(a3, bfr[3], acc, 0, 0, 0);

    const int i0 = rowChunk + lcr + quad * 4;   // this lane's first sorted row

    if (__builtin_expect((hi > i0) & (lo < i0 + 4), 0)) {
      // pos-intersecting tile (~3%, near-wave-uniform: consecutive sorted cols)
      #pragma unroll
      for (int r = 0; r < 4; ++r) {
        const float a = acc[r];
        const int i = i0 + r;
        const float pm = (i >= lo && i < hi) ? 1.f : 0.f;
        const f32x2 av = {a, a}, p2 = {pm, pm};
        const f32x2 d01 = pkclamp01(__builtin_elementwise_fma(av, (f32x2){5.f, 5.f},
                                                              (f32x2){-1.f, 0.f}));
        const f32x2 d23 = pkclamp01(__builtin_elementwise_fma(av, (f32x2){5.f, 5.f},
                                                              (f32x2){1.f, 2.f}));
        C01 += d01; C23 += d23;
        Cp01 = __builtin_elementwise_fma(p2, d01, Cp01);
        Cp23 = __builtin_elementwise_fma(p2, d23, Cp23);
      }
    } else {
      // fast path: bins 3..6 exact for all t: H[k] = clamp01(5a + (k-4))
      #pragma unroll
      for (int r = 0; r < 4; ++r) {
        const f32x2 av = {acc[r], acc[r]};
        C01 += pkclamp01(__builtin_elementwise_fma(av, (f32x2){5.f, 5.f},
                                                   (f32x2){-1.f, 0.f}));
        C23 += pkclamp01(__builtin_elementwise_fma(av, (f32x2){5.f, 5.f},
                                                   (f32x2){1.f, 2.f}));
      }
    }

    const float mabs = fmaxf(fmaxf(fabsf(acc[0]), fabsf(acc[1])),
                             fmaxf(fabsf(acc[2]), fabsf(acc[3])));
    if (__builtin_expect(mabs > 0.4f, 0)) {
      #pragma unroll
      for (int r = 0; r < 4; ++r) {
        const float a = acc[r];
        if (fabsf(a) <= 0.4f) continue;
        const int i = i0 + r;
        const float d0 = clamp01(fmaf(a, 5.f, -1.f));
        const float d1 = clamp01(a * 5.f);
        const float d2 = clamp01(fmaf(a, 5.f, 1.f));
        const float d3 = clamp01(fmaf(a, 5.f, 2.f));
        if (i == jcol) {
          // diagonal: cancel fast C and Cp contributions + bins>=7 base (+1)
          C01 -= (f32x2){d0, d1};  C23 -= (f32x2){d2, d3};
          Cp01 -= (f32x2){d0, d1}; Cp23 -= (f32x2){d2, d3};
          #pragma unroll
          for (int k = 7; k <= 10; ++k)
            atomicAdd(&gA[jcol * AROW + k], (unsigned)(-65536));
        } else {
          const bool isPos = (i >= lo) & (i < hi);
          const float t = fmaf(a, -5.f, 5.f);
          #pragma unroll
          for (int k = 0; k <= 2; ++k) {       // assumed cumulative 0
            const int q = (int)(clamp01((float)(k + 1) - t) * 65536.f + 0.5f);
            if (q) {
              atomicAdd(&gA[jcol * AROW + k], (unsigned)q);
              if (isPos) atomicAdd(&gAp[jcol * AROW + k], (unsigned)q);
            }
          }
          #pragma unroll
          for (int k = 7; k <= 10; ++k) {      // assumed cumulative 1
            const int q = (int)((clamp01((float)(k + 1) - t) - 1.f) * 65536.f - 0.5f);
            if (q) {
              atomicAdd(&gA[jcol * AROW + k], (unsigned)q);
              if (isPos) atomicAdd(&gAp[jcol * AROW + k], (unsigned)q);
            }
          }
        }
      }
    }
  };

  stage(0, 0);
  __syncthreads();             // panel 0 drained

  #pragma unroll 1
  for (int p = 0; p < NPANEL; ++p) {
    const int cur = p & 1;
    if (p + 1 < NPANEL) stage(p + 1, cur ^ 1);   // async DMA behind this panel
    tile16(&sA[cur][0],        p * 32);
    tile16(&sA[cur][16 * 128], p * 32 + 16);
    __syncthreads();
  }

  // reduce across the 4 quads sharing each column (lane ^16, ^32)
  #pragma unroll
  for (int m = 16; m < 64; m <<= 1) {
    C01.x  += __shfl_xor(C01.x,  m, 64); C01.y  += __shfl_xor(C01.y,  m, 64);
    C23.x  += __shfl_xor(C23.x,  m, 64); C23.y  += __shfl_xor(C23.y,  m, 64);
    Cp01.x += __shfl_xor(Cp01.x, m, 64); Cp01.y += __shfl_xor(Cp01.y, m, 64);
    Cp23.x += __shfl_xor(Cp23.x, m, 64); Cp23.y += __shfl_xor(Cp23.y, m, 64);
  }

  if (quad == 0) {
    const float Cv[4]  = {C01.x, C01.y, C23.x, C23.y};
    const float Cpv[4] = {Cp01.x, Cp01.y, Cp23.x, Cp23.y};
    #pragma unroll
    for (int k = 0; k < 4; ++k) {
      atomicAdd(&gS[jcol * 4 + k],  (unsigned)(int)lrintf(Cv[k]  * 65536.f));
      atomicAdd(&gSp[jcol * 4 + k], (unsigned)(int)lrintf(Cpv[k] * 65536.f));
    }
  }
}

// ---- epilogue: per-sorted-row AP + final loss (mean is permutation-invariant) ----
__global__ __launch_bounds__(256) void epilogue_kernel(
    const unsigned* __restrict__ gS, const unsigned* __restrict__ gSp,
    const unsigned* __restrict__ gA, const unsigned* __restrict__ gAp,
    const int* __restrict__ classOf, const int* __restrict__ cnt,
    float* __restrict__ accum, unsigned* __restrict__ done,
    float* __restrict__ out) {
  const int i = blockIdx.x * 256 + threadIdx.x;
  const int np = cnt[classOf[i]] - 1;   // N_pos = classCount - 1
  float ap = 0.f, val = 0.f, HpPrev = 0.f;
  #pragma unroll
  for (int b = 0; b <= 10; ++b) {
    const float baseH  = (b < 3) ? 0.f
                       : (b < 7) ? (float)(int)gS[i * 4 + (b - 3)]  * INV64K : 8192.f;
    const float basePp = (b < 3) ? 0.f
                       : (b < 7) ? (float)(int)gSp[i * 4 + (b - 3)] * INV64K : (float)np;
    const float H  = baseH  + (float)(int)gA[i * AROW + b]  * INV64K;
    const float Hp = basePp + (float)(int)gAp[i * AROW + b] * INV64K;
    const float hp = Hp - HpPrev;
    HpPrev = Hp;
    if (H > 1e-6f) ap += hp * Hp / H;
  }
  if (np > 0) { ap /= (float)np; val = 1.f; } else ap = 0.f;

  __shared__ float sa[256], sv[256];
  sa[threadIdx.x] = ap; sv[threadIdx.x] = val;
  __syncthreads();
  for (int s = 128; s > 0; s >>= 1) {
    if (threadIdx.x < s) {
      sa[threadIdx.x] += sa[threadIdx.x + s];
      sv[threadIdx.x] += sv[threadIdx.x + s];
    }
    __syncthreads();
  }
  if (threadIdx.x == 0) {
    atomicAdd(&accum[0], sa[0]);
    atomicAdd(&accum[1], sv[0]);
    __threadfence();
    const unsigned prev = atomicAdd(done, 1u);
    if (prev == gridDim.x - 1) {
      const float a = atomicAdd(&accum[0], 0.f);   // coherent reads
      const float c = atomicAdd(&accum[1], 0.f);
      out[0] = 1.f - (c > 0.f ? a / c : 0.f);
    }
  }
}

extern "C" void kernel_launch(void* const* d_in, const int* in_sizes, int n_in,
                              void* d_out, int out_size, void* d_ws, size_t ws_size,
                              hipStream_t stream) {
  const float* x      = (const float*)d_in[0];
  const int*   labels = (const int*)d_in[1];
  float* out = (float*)d_out;

  char* ws = (char*)d_ws;
  unsigned short* xb = (unsigned short*)(ws + OFF_XB);
  unsigned* gS    = (unsigned*)(ws + OFF_GS);
  unsigned* gSp   = (unsigned*)(ws + OFF_GSP);
  unsigned* gA    = (unsigned*)(ws + OFF_GA);
  unsigned* gAp   = (unsigned*)(ws + OFF_GAP);
  float*    accum = (float*)(ws + OFF_AC);
  unsigned* done  = (unsigned*)(ws + OFF_AC + 8);
  int*      cnt   = (int*)(ws + OFF_CNT);
  int*      ofs   = (int*)(ws + OFF_OFS);
  int*      intra = (int*)(ws + OFF_INTRA);
  int*      cls   = (int*)(ws + OFF_CLS);

  prep_count_kernel<<<1, 256, 0, stream>>>(labels, cnt, ofs, intra);
  prep_scatter_kernel<<<512, 256, 0, stream>>>(x, labels, ofs, intra, xb, cls,
                                               (uint4*)(ws + OFF_GS));
  fastap_main_kernel<<<dim3(NS / 64, NS / ROWCHUNK), 256, 0, stream>>>(
      xb, cls, cnt, ofs, gS, gSp, gA, gAp);
  epilogue_kernel<<<NS / 256, 256, 0, stream>>>(gS, gSp, gA, gAp, cls, cnt,
                                                accum, done, out);
}